// Round 16
// baseline (315.923 us; speedup 1.0000x reference)
//
#include <hip/hip_runtime.h>
#include <math.h>

#define NC    30
#define D     300
#define WIN   100
#define TOPK  25
#define NEGV  -1e10f
#define NKS   19           // 19*16 = 304 >= 300
#define AST   312          // A-plane LDS row stride in shorts (624 B)

typedef __attribute__((ext_vector_type(8)))  short short8;
typedef __attribute__((ext_vector_type(16))) float f32x16;
typedef __attribute__((ext_vector_type(4)))  unsigned int uint4v;

__device__ inline unsigned short bftrunc(float f) {
    return (unsigned short)(__builtin_bit_cast(unsigned int, f) >> 16);
}
__device__ inline float bfval(unsigned short b) {
    return __builtin_bit_cast(float, (unsigned int)b << 16);
}
__device__ inline void split8(const float* v, short8& hi, short8& lo) {
    #pragma unroll
    for (int j = 0; j < 8; ++j) {
        unsigned short hb = bftrunc(v[j]);
        float lf = v[j] - bfval(hb);
        hi[j] = (short)hb;
        lo[j] = (short)bftrunc(lf);
    }
}

__global__ __launch_bounds__(256, 4)
void fused_mention_kernel(const float* __restrict__ E,
                          const float* __restrict__ T,
                          const void*  __restrict__ maskp,
                          const float* __restrict__ B1,
                          const float* __restrict__ B2,
                          float* __restrict__ out)
{
    const int n     = blockIdx.x;
    const int tid   = threadIdx.x;
    const int wv    = tid >> 6;
    const int lane  = tid & 63;
    const int arow  = lane & 31;          // candidate row (A) / token col (B)
    const int khalf = (lane >> 5) * 8;

    __shared__ __align__(16) short Ah[NC * AST];   // 18.7 KB bf16-hi of E*B2
    __shared__ __align__(16) short Al[NC * AST];   // 18.7 KB bf16-lo
    __shared__ float ts[WIN];

    // ---- mask dtype detect, per-wave: int32 has zero bytes at %4!=0 ----
    int found;
    {
        const uint4v* m4 = (const uint4v*)maskp;
        uint4v w = m4[wv * 64 + lane];
        found = (((w.x | w.y | w.z | w.w) & 0xFFFFFF00u) != 0u) ? 1 : 0;
    }
    const bool bytemask = (__ballot(found) != 0ULL);

    // ---- valid-prefix length L, per-wave ----
    int v0m = 0, v1m = 0;
    if (bytemask) {
        const unsigned char* mb = (const unsigned char*)maskp + (size_t)n * WIN;
        v0m = mb[lane] != 0;
        if (lane + 64 < WIN) v1m = mb[lane + 64] != 0;
    } else {
        const int* mi = (const int*)maskp + (size_t)n * WIN;
        v0m = mi[lane] != 0;
        if (lane + 64 < WIN) v1m = mi[lane + 64] != 0;
    }
    const int L  = __popcll(__ballot(v0m)) + __popcll(__ballot(v1m));
    const int Lc = (L > 0) ? L : 1;

    // ---- B1 == B2 check (enables vals-from-scores identity) ----
    int neq = 0;
    #pragma unroll
    for (int k = 0; k < 5; ++k) {
        const int d = lane + 64 * k;
        if (d < D) neq |= (B1[d] != B2[d]) ? 1 : 0;
    }
    const bool beq = (__ballot(neq) == 0ULL);   // block-uniform

    // ---- stage A = E * B_diag2 into LDS as bf16 hi/lo (flat, coalesced) ----
    for (int i = tid; i < NC * 38; i += 256) {
        const int row = i / 38;
        const int c8  = i - row * 38;
        const int col = c8 * 8;
        const float* src = E + ((size_t)n * NC + row) * D + col;
        float v[8];
        float4 q0 = *reinterpret_cast<const float4*>(src);
        float4 b0 = *reinterpret_cast<const float4*>(B2 + col);
        v[0] = q0.x * b0.x; v[1] = q0.y * b0.y;
        v[2] = q0.z * b0.z; v[3] = q0.w * b0.w;
        if (c8 < 37) {
            float4 q1 = *reinterpret_cast<const float4*>(src + 4);
            float4 b1 = *reinterpret_cast<const float4*>(B2 + col + 4);
            v[4] = q1.x * b1.x; v[5] = q1.y * b1.y;
            v[6] = q1.z * b1.z; v[7] = q1.w * b1.w;
        } else {
            v[4] = v[5] = v[6] = v[7] = 0.f;      // cols 300..303 zero
        }
        short8 hi, lo;
        split8(v, hi, lo);
        *reinterpret_cast<short8*>(Ah + row * AST + col) = hi;
        *reinterpret_cast<short8*>(Al + row * AST + col) = lo;
    }

    const int ntiles = (L + 31) >> 5;
    const int t0 = wv * 32;
    const float* Tn = T + (size_t)n * WIN * D;
    const float* bp = Tn + (size_t)min(t0 + arow, Lc - 1) * D;
    const int aoff = min(arow, NC - 1) * AST + khalf;

    // ---- preload GEMM ring steps 0..3 BEFORE the barrier (hides HBM latency) ----
    float4 q0r[4], q1r[4];
    if (wv < ntiles) {
        #pragma unroll
        for (int s = 0; s < 4; ++s) {
            const int kb = 16 * s + khalf;
            q0r[s] = *reinterpret_cast<const float4*>(bp + kb);
            q1r[s] = *reinterpret_cast<const float4*>(bp + kb + 4);
        }
    }
    __syncthreads();                              // #1: A staged

    // ---- EXACT score GEMM (3-term split): wave wv owns tile wv ----
    f32x16 c;
    #pragma unroll
    for (int r = 0; r < 16; ++r) c[r] = 0.f;
    float m = NEGV;
    if (wv < ntiles) {
        f32x16 cB;
        #pragma unroll
        for (int r = 0; r < 16; ++r) cB[r] = 0.f;
        #pragma unroll
        for (int s = 0; s < NKS; ++s) {
            const int slot = s & 3;               // static after unroll
            float4 q0 = q0r[slot], q1 = q1r[slot];
            if (s + 4 < NKS) {                    // prefetch step s+4
                const int kb2 = 16 * (s + 4) + khalf;
                q0r[slot] = *reinterpret_cast<const float4*>(bp + kb2);
                q1r[slot] = (kb2 + 8 <= D)
                          ? *reinterpret_cast<const float4*>(bp + kb2 + 4)
                          : make_float4(0.f, 0.f, 0.f, 0.f);
            }
            short8 ah = *reinterpret_cast<const short8*>(Ah + aoff + 16 * s);
            short8 al = *reinterpret_cast<const short8*>(Al + aoff + 16 * s);
            float v[8] = {q0.x, q0.y, q0.z, q0.w, q1.x, q1.y, q1.z, q1.w};
            short8 bh, bl;
            split8(v, bh, bl);
            if (s & 1) {                          // dual accumulators
                cB = __builtin_amdgcn_mfma_f32_32x32x16_bf16(ah, bh, cB, 0, 0, 0);
                cB = __builtin_amdgcn_mfma_f32_32x32x16_bf16(al, bh, cB, 0, 0, 0);
                cB = __builtin_amdgcn_mfma_f32_32x32x16_bf16(ah, bl, cB, 0, 0, 0);
            } else {
                c  = __builtin_amdgcn_mfma_f32_32x32x16_bf16(ah, bh, c, 0, 0, 0);
                c  = __builtin_amdgcn_mfma_f32_32x32x16_bf16(al, bh, c, 0, 0, 0);
                c  = __builtin_amdgcn_mfma_f32_32x32x16_bf16(ah, bl, c, 0, 0, 0);
            }
        }
        #pragma unroll
        for (int r = 0; r < 16; ++r) c[r] += cB[r];
        // pad candidate rows 30,31 (regs 14,15 on lanes >= 32) -> -inf
        if (lane >= 32) { c[14] = -__builtin_inff(); c[15] = -__builtin_inff(); }
        m = c[0];
        #pragma unroll
        for (int r = 1; r < 16; ++r) m = fmaxf(m, c[r]);
        m = fmaxf(m, __shfl_xor(m, 32));
    }
    if (lane < 32 && t0 + arow < WIN)
        ts[t0 + arow] = (wv < ntiles && t0 + arow < L) ? m : NEGV;
    __syncthreads();                              // #2: ts complete (last barrier)

    if (wv >= ntiles && !(wv == 0)) return;       // idle waves retire now
    if (!beq && wv != 0) return;                  // fallback is wave0-only

    // ---- redundant per-wave top-25 (lower-index tie-break) + softmax ----
    const float NINF = -__builtin_inff();
    float va = ts[lane];
    float vb = (lane + 64 < WIN) ? ts[lane + 64] : NINF;
    float sc = 0.f, mx = 0.f;
    int   ixr = 0;
    for (int t = 0; t < TOPK; ++t) {
        float v0; int i0;
        if (vb > va) { v0 = vb; i0 = lane + 64; } else { v0 = va; i0 = lane; }
        #pragma unroll
        for (int s = 32; s >= 1; s >>= 1) {
            float ov = __shfl_xor(v0, s);
            int   oi = __shfl_xor(i0, s);
            if (ov > v0 || (ov == v0 && oi < i0)) { v0 = ov; i0 = oi; }
        }
        if (t == 0) mx = v0;
        if (lane == t) { sc = v0; ixr = i0; }
        if (i0 == lane) va = NINF;
        else if (i0 == lane + 64) vb = NINF;
    }
    float p = (lane < TOPK) ? expf(sc - mx) : 0.f;
    float s1 = p;
    #pragma unroll
    for (int s = 32; s >= 1; s >>= 1) s1 += __shfl_xor(s1, s);
    p = p / s1;
    float s2 = p;   // reference renormalizes a second time
    #pragma unroll
    for (int s = 32; s >= 1; s >>= 1) s2 += __shfl_xor(s2, s);
    p = p / s2;

    if (beq) {
        // ---- vals[c] += sum_{t in my tile} p_t * S[c, idx_t]; atomic epilogue ----
        float vacc[16];
        #pragma unroll
        for (int r = 0; r < 16; ++r) vacc[r] = 0.f;
        if (wv < ntiles) {
            for (int t = 0; t < TOPK; ++t) {
                const float pb = __shfl(p, t);
                const int   ib = __shfl(ixr, t);
                if ((ib >> 5) == wv) {            // wave-uniform
                    if ((lane & 31) == (ib & 31)) {
                        #pragma unroll
                        for (int r = 0; r < 16; ++r) vacc[r] += pb * c[r];
                    }
                }
            }
            #pragma unroll
            for (int r = 0; r < 16; ++r) {
                float s = vacc[r];
                s += __shfl_xor(s, 1);  s += __shfl_xor(s, 2);
                s += __shfl_xor(s, 4);  s += __shfl_xor(s, 8);
                s += __shfl_xor(s, 16);
                vacc[r] = s;
            }
            if ((lane & 31) == 0) {               // lanes 0 and 32
                #pragma unroll
                for (int r = 0; r < 16; ++r) {
                    const int row = (r & 3) + 8 * (r >> 2) + 4 * (lane >> 5);
                    if (row < NC)
                        atomicAdd(&out[(size_t)n * NC + row], vacc[r]);
                }
            }
        }
    } else {
        // ---- fallback (B1 != B2): wave0 register-resident fcs + vals ----
        float fc[5] = {0.f, 0.f, 0.f, 0.f, 0.f};
        for (int t = 0; t < TOPK; ++t) {
            const float pb = __shfl(p, t);
            const int   ib = __shfl(ixr, t);
            const float* Trow = Tn + (size_t)ib * D;
            #pragma unroll
            for (int c5 = 0; c5 < 5; ++c5) {
                const int dim = c5 * 64 + lane;
                if (dim < D) fc[c5] += pb * Trow[dim];
            }
        }
        float acc2[NC];
        #pragma unroll
        for (int cc = 0; cc < NC; ++cc) acc2[cc] = 0.f;
        #pragma unroll
        for (int c5 = 0; c5 < 5; ++c5) {
            const int dim  = c5 * 64 + lane;
            const int dimc = min(dim, D - 1);
            const float g  = (dim < D) ? B1[dim] * fc[c5] : 0.f;
            const float* Eb = E + (size_t)n * NC * D + dimc;
            #pragma unroll
            for (int cc = 0; cc < NC; ++cc)
                acc2[cc] += Eb[(size_t)cc * D] * g;
        }
        #pragma unroll
        for (int cc = 0; cc < NC; ++cc) {
            float s = acc2[cc];
            #pragma unroll
            for (int sft = 32; sft >= 1; sft >>= 1) s += __shfl_xor(s, sft);
            if (lane == cc) out[(size_t)n * NC + cc] = s;
        }
    }
}

extern "C" void kernel_launch(void* const* d_in, const int* in_sizes, int n_in,
                              void* d_out, int out_size, void* d_ws, size_t ws_size,
                              hipStream_t stream)
{
    const float* E  = (const float*)d_in[0];
    const float* T  = (const float*)d_in[1];
    const void*  M  = d_in[2];
    const float* B1 = (const float*)d_in[3];
    const float* B2 = (const float*)d_in[4];
    float* out = (float*)d_out;
    const int n = in_sizes[0] / (NC * D);   // number of mentions
    // zero the output: atomic epilogue accumulates into it (also resets replays)
    hipMemsetAsync(out, 0, (size_t)out_size * sizeof(float), stream);
    fused_mention_kernel<<<n, 256, 0, stream>>>(E, T, M, B1, B2, out);
}

// Round 17
// 274.504 us; speedup vs baseline: 1.1509x; 1.1509x over previous
//
#include <hip/hip_runtime.h>
#include <math.h>

#define NC    30
#define D     300
#define WIN   100
#define TOPK  25
#define NEGV  -1e10f
#define NKS   19           // 19*16 = 304 >= 300
#define AST   312          // A-plane LDS row stride in shorts (624 B)

typedef __attribute__((ext_vector_type(8)))  short short8;
typedef __attribute__((ext_vector_type(16))) float f32x16;
typedef __attribute__((ext_vector_type(4)))  unsigned int uint4v;

__device__ inline unsigned short bftrunc(float f) {
    return (unsigned short)(__builtin_bit_cast(unsigned int, f) >> 16);
}
__device__ inline float bfval(unsigned short b) {
    return __builtin_bit_cast(float, (unsigned int)b << 16);
}

// split 8 f32 into bf16 hi/lo planes via HW packed conversion (RNE):
// hi = bf16_rne(v), lo = bf16_rne(v - float(hi));  v ~= hi + lo, |resid| ~ 2^-19|v|
__device__ inline void split8(const float* v, short8& hi, short8& lo) {
    uint4v hp, lp;
    float lf[8];
    #pragma unroll
    for (int j = 0; j < 4; ++j) {
        unsigned int pk;
        asm("v_cvt_pk_bf16_f32 %0, %1, %2"
            : "=v"(pk) : "v"(v[2 * j]), "v"(v[2 * j + 1]));
        hp[j] = pk;
        lf[2 * j]     = v[2 * j]     - __builtin_bit_cast(float, pk << 16);
        lf[2 * j + 1] = v[2 * j + 1] - __builtin_bit_cast(float, pk & 0xFFFF0000u);
    }
    #pragma unroll
    for (int j = 0; j < 4; ++j) {
        unsigned int pk;
        asm("v_cvt_pk_bf16_f32 %0, %1, %2"
            : "=v"(pk) : "v"(lf[2 * j]), "v"(lf[2 * j + 1]));
        lp[j] = pk;
    }
    hi = __builtin_bit_cast(short8, hp);
    lo = __builtin_bit_cast(short8, lp);
}

__global__ __launch_bounds__(256, 4)
void fused_mention_kernel(const float* __restrict__ E,
                          const float* __restrict__ T,
                          const void*  __restrict__ maskp,
                          const float* __restrict__ B1,
                          const float* __restrict__ B2,
                          float* __restrict__ out)
{
    const int n     = blockIdx.x;
    const int tid   = threadIdx.x;
    const int wv    = tid >> 6;
    const int lane  = tid & 63;
    const int arow  = lane & 31;          // candidate row (A) / token col (B)
    const int khalf = (lane >> 5) * 8;

    __shared__ __align__(16) short Ah[NC * AST];   // 18.7 KB bf16-hi of E*B2
    __shared__ __align__(16) short Al[NC * AST];   // 18.7 KB bf16-lo
    __shared__ __align__(16) float fcsL[D];        // fallback path only
    __shared__ float ts[WIN];
    __shared__ float bscore[TOPK];
    __shared__ int   bidx[TOPK];
    __shared__ float bprob[TOPK];
    __shared__ float vredS[4][32];

    if (tid < WIN) ts[tid] = NEGV;        // covered by the stage barrier below

    // ---- mask dtype detect, per-wave (no barrier): int32 has zero bytes %4!=0 ----
    int found;
    {
        const uint4v* m4 = (const uint4v*)maskp;
        uint4v w = m4[wv * 64 + lane];    // wave w scans bytes [1024w, 1024w+1024)
        found = (((w.x | w.y | w.z | w.w) & 0xFFFFFF00u) != 0u) ? 1 : 0;
    }
    const bool bytemask = (__ballot(found) != 0ULL);

    // ---- valid-prefix length L, per-wave (redundant, L1-hot, no LDS) ----
    int v0m = 0, v1m = 0;
    if (bytemask) {
        const unsigned char* mb = (const unsigned char*)maskp + (size_t)n * WIN;
        v0m = mb[lane] != 0;
        if (lane + 64 < WIN) v1m = mb[lane + 64] != 0;
    } else {
        const int* mi = (const int*)maskp + (size_t)n * WIN;
        v0m = mi[lane] != 0;
        if (lane + 64 < WIN) v1m = mi[lane + 64] != 0;
    }
    const int L  = __popcll(__ballot(v0m)) + __popcll(__ballot(v1m));
    const int Lc = (L > 0) ? L : 1;

    // ---- B1 == B2 check (enables vals-from-scores identity) ----
    int neq = 0;
    #pragma unroll
    for (int k = 0; k < 5; ++k) {
        const int d = lane + 64 * k;
        if (d < D) neq |= (B1[d] != B2[d]) ? 1 : 0;
    }
    const bool beq = (__ballot(neq) == 0ULL);   // block-uniform (global data)

    // ---- stage A = E * B_diag2 into LDS as bf16 hi/lo ----
    {
        const int srow = tid & 31;        // rows 30,31 idle (16 threads)
        const int scol = tid >> 5;        // 0..7
        if (srow < NC) {
            #pragma unroll
            for (int k = 0; k < 5; ++k) {
                const int c8 = scol + 8 * k;          // 0..39
                if (c8 < 38) {
                    const int col = c8 * 8;
                    const float* src = E + ((size_t)n * NC + srow) * D + col;
                    float v[8];
                    float4 q0 = *reinterpret_cast<const float4*>(src);
                    float4 b0 = *reinterpret_cast<const float4*>(B2 + col);
                    v[0] = q0.x * b0.x; v[1] = q0.y * b0.y;
                    v[2] = q0.z * b0.z; v[3] = q0.w * b0.w;
                    if (c8 < 37) {
                        float4 q1 = *reinterpret_cast<const float4*>(src + 4);
                        float4 b1 = *reinterpret_cast<const float4*>(B2 + col + 4);
                        v[4] = q1.x * b1.x; v[5] = q1.y * b1.y;
                        v[6] = q1.z * b1.z; v[7] = q1.w * b1.w;
                    } else {
                        v[4] = v[5] = v[6] = v[7] = 0.f;   // cols 300..303 zero
                    }
                    short8 hi, lo;
                    split8(v, hi, lo);
                    *reinterpret_cast<short8*>(Ah + srow * AST + col) = hi;
                    *reinterpret_cast<short8*>(Al + srow * AST + col) = lo;
                }
            }
        }
    }

    const int ntiles = (L + 31) >> 5;
    const int t0 = wv * 32;
    const float* Tn = T + (size_t)n * WIN * D;
    const float* bp = Tn + (size_t)min(t0 + arow, Lc - 1) * D;

    // ---- preload GEMM ring steps 0..3 BEFORE the barrier (hides HBM latency) ----
    float4 q0r[4], q1r[4];
    if (wv < ntiles) {
        #pragma unroll
        for (int s = 0; s < 4; ++s) {
            const int kb = 16 * s + khalf;
            q0r[s] = *reinterpret_cast<const float4*>(bp + kb);
            q1r[s] = *reinterpret_cast<const float4*>(bp + kb + 4);
        }
    }
    __syncthreads();                                  // A staged, ts init'd

    // ---- score GEMM: wave wv owns tile wv; 4-step prefetch ring ----
    f32x16 c;
    #pragma unroll
    for (int r = 0; r < 16; ++r) c[r] = 0.f;
    if (wv < ntiles) {
        const int aoff = min(arow, NC - 1) * AST + khalf;   // rows 30,31 clamp (masked)
        #pragma unroll
        for (int s = 0; s < NKS; ++s) {
            const int slot = s & 3;                   // static after unroll
            float4 q0 = q0r[slot], q1 = q1r[slot];
            if (s + 4 < NKS) {                        // prefetch step s+4
                const int kb2 = 16 * (s + 4) + khalf;
                q0r[slot] = *reinterpret_cast<const float4*>(bp + kb2);
                q1r[slot] = (kb2 + 8 <= D)
                          ? *reinterpret_cast<const float4*>(bp + kb2 + 4)
                          : make_float4(0.f, 0.f, 0.f, 0.f);
            }
            short8 ah = *reinterpret_cast<const short8*>(Ah + aoff + 16 * s);
            short8 al = *reinterpret_cast<const short8*>(Al + aoff + 16 * s);
            float v[8] = {q0.x, q0.y, q0.z, q0.w, q1.x, q1.y, q1.z, q1.w};
            short8 bh, bl;
            split8(v, bh, bl);
            c = __builtin_amdgcn_mfma_f32_32x32x16_bf16(ah, bh, c, 0, 0, 0);
            c = __builtin_amdgcn_mfma_f32_32x32x16_bf16(al, bh, c, 0, 0, 0);
            c = __builtin_amdgcn_mfma_f32_32x32x16_bf16(ah, bl, c, 0, 0, 0);
        }
        // pad candidate rows 30,31 (regs 14,15 on lanes >= 32) -> -inf
        if (lane >= 32) { c[14] = -__builtin_inff(); c[15] = -__builtin_inff(); }
        float m = c[0];
        #pragma unroll
        for (int r = 1; r < 16; ++r) m = fmaxf(m, c[r]);
        m = fmaxf(m, __shfl_xor(m, 32));
        if (lane < 32 && t0 + arow < L) ts[t0 + arow] = m;
    }
    __syncthreads();                                  // ts complete

    // ---- top-25 (wave 0, lower-index tie-break) + double-normalized softmax ----
    if (tid < 64) {
        float va = ts[tid];
        float vb = (tid + 64 < WIN) ? ts[tid + 64] : -__builtin_inff();
        float mx = 0.f;
        for (int t = 0; t < TOPK; ++t) {
            float v0; int i0;
            if (vb > va) { v0 = vb; i0 = tid + 64; } else { v0 = va; i0 = tid; }
            #pragma unroll
            for (int s = 32; s >= 1; s >>= 1) {
                float ov = __shfl_xor(v0, s);
                int   oi = __shfl_xor(i0, s);
                if (ov > v0 || (ov == v0 && oi < i0)) { v0 = ov; i0 = oi; }
            }
            if (t == 0) mx = v0;
            if (tid == 0) { bscore[t] = v0; bidx[t] = i0; }
            if (i0 == tid) va = -__builtin_inff();
            else if (i0 == tid + 64) vb = -__builtin_inff();
        }
        float sc = (tid < TOPK) ? bscore[tid] : 0.f;
        float p  = (tid < TOPK) ? expf(sc - mx) : 0.f;
        float s1 = p;
        #pragma unroll
        for (int s = 32; s >= 1; s >>= 1) s1 += __shfl_xor(s1, s);
        p = p / s1;
        float s2 = p;   // reference renormalizes a second time
        #pragma unroll
        for (int s = 32; s >= 1; s >>= 1) s2 += __shfl_xor(s2, s);
        p = p / s2;
        if (tid < TOPK) bprob[tid] = p;
    }
    __syncthreads();                                  // bprob/bidx visible

    if (beq) {
        // ---- vals[c] = sum_t p_t * S[c, idx_t] straight from the accumulators ----
        float vacc[16];
        #pragma unroll
        for (int r = 0; r < 16; ++r) vacc[r] = 0.f;
        if (wv < ntiles) {
            for (int t = 0; t < TOPK; ++t) {
                const int ix = bidx[t];
                if ((ix >> 5) == wv) {                // wave-uniform branch
                    const float p = bprob[t];
                    if ((lane & 31) == (ix & 31)) {   // owning lanes (2 of 64)
                        #pragma unroll
                        for (int r = 0; r < 16; ++r) vacc[r] += p * c[r];
                    }
                }
            }
        }
        // butterfly-sum within each 32-lane half (rows differ per half)
        #pragma unroll
        for (int r = 0; r < 16; ++r) {
            float s = vacc[r];
            s += __shfl_xor(s, 1);  s += __shfl_xor(s, 2);
            s += __shfl_xor(s, 4);  s += __shfl_xor(s, 8);
            s += __shfl_xor(s, 16);
            vacc[r] = s;
        }
        if ((lane & 31) == 0) {                       // lanes 0 and 32
            #pragma unroll
            for (int r = 0; r < 16; ++r) {
                const int row = (r & 3) + 8 * (r >> 2) + 4 * (lane >> 5);
                vredS[wv][row] = vacc[r];
            }
        }
        __syncthreads();
        if (tid < NC) {
            out[(size_t)n * NC + tid] = vredS[0][tid] + vredS[1][tid]
                                      + vredS[2][tid] + vredS[3][tid];
        }
    } else {
        // ---- fallback (B1 != B2): fcs gather + vals with E re-read ----
        for (int d = tid; d < D; d += 256) {
            float acc = 0.f;
            #pragma unroll 5
            for (int t = 0; t < TOPK; ++t)
                acc += bprob[t] * Tn[(size_t)bidx[t] * D + d];
            fcsL[d] = acc;
        }
        __syncthreads();
        {
            const int dg = tid >> 5;
            const int d0 = dg * 40;
            const bool full = (dg < 7);
            const int cg = arow;
            const bool cok = (cg < NC);
            float acc2 = 0.f;
            const float* Erow = E + ((size_t)n * NC + (cok ? cg : 0)) * D + d0;
            #pragma unroll
            for (int j = 0; j < 5; ++j) {
                float4 ev = *reinterpret_cast<const float4*>(Erow + 4 * j);
                float4 bv = *reinterpret_cast<const float4*>(B1 + d0 + 4 * j);
                float4 fv = *reinterpret_cast<const float4*>(fcsL + d0 + 4 * j);
                acc2 += ev.x * bv.x * fv.x + ev.y * bv.y * fv.y
                      + ev.z * bv.z * fv.z + ev.w * bv.w * fv.w;
            }
            if (full) {
                #pragma unroll
                for (int j = 5; j < 10; ++j) {
                    float4 ev = *reinterpret_cast<const float4*>(Erow + 4 * j);
                    float4 bv = *reinterpret_cast<const float4*>(B1 + d0 + 4 * j);
                    float4 fv = *reinterpret_cast<const float4*>(fcsL + d0 + 4 * j);
                    acc2 += ev.x * bv.x * fv.x + ev.y * bv.y * fv.y
                          + ev.z * bv.z * fv.z + ev.w * bv.w * fv.w;
                }
            }
            if (!cok) acc2 = 0.f;
            acc2 += __shfl_xor(acc2, 32);
            if (lane < 32) vredS[wv][cg] = acc2;
        }
        __syncthreads();
        if (tid < NC) {
            out[(size_t)n * NC + tid] = vredS[0][tid] + vredS[1][tid]
                                      + vredS[2][tid] + vredS[3][tid];
        }
    }
}

extern "C" void kernel_launch(void* const* d_in, const int* in_sizes, int n_in,
                              void* d_out, int out_size, void* d_ws, size_t ws_size,
                              hipStream_t stream)
{
    const float* E  = (const float*)d_in[0];
    const float* T  = (const float*)d_in[1];
    const void*  M  = d_in[2];
    const float* B1 = (const float*)d_in[3];
    const float* B2 = (const float*)d_in[4];
    float* out = (float*)d_out;
    const int n = in_sizes[0] / (NC * D);   // number of mentions
    fused_mention_kernel<<<n, 256, 0, stream>>>(E, T, M, B1, B2, out);
}

// Round 18
// 268.326 us; speedup vs baseline: 1.1774x; 1.0230x over previous
//
#include <hip/hip_runtime.h>
#include <math.h>

#define NC    30
#define D     300
#define WIN   100
#define TOPK  25
#define NEGV  -1e10f
#define NKS   19           // 19*16 = 304 >= 300
#define AST   312          // A-plane LDS row stride in shorts (624 B)

typedef __attribute__((ext_vector_type(8)))  short short8;
typedef __attribute__((ext_vector_type(16))) float f32x16;
typedef __attribute__((ext_vector_type(4)))  unsigned int uint4v;

__device__ inline unsigned short bftrunc(float f) {
    return (unsigned short)(__builtin_bit_cast(unsigned int, f) >> 16);
}
__device__ inline float bfval(unsigned short b) {
    return __builtin_bit_cast(float, (unsigned int)b << 16);
}

// split 8 f32 into bf16 hi/lo planes via HW packed conversion (RNE):
// hi = bf16_rne(v), lo = bf16_rne(v - float(hi));  v ~= hi + lo
__device__ inline void split8(const float* v, short8& hi, short8& lo) {
    uint4v hp, lp;
    float lf[8];
    #pragma unroll
    for (int j = 0; j < 4; ++j) {
        unsigned int pk;
        asm("v_cvt_pk_bf16_f32 %0, %1, %2"
            : "=v"(pk) : "v"(v[2 * j]), "v"(v[2 * j + 1]));
        hp[j] = pk;
        lf[2 * j]     = v[2 * j]     - __builtin_bit_cast(float, pk << 16);
        lf[2 * j + 1] = v[2 * j + 1] - __builtin_bit_cast(float, pk & 0xFFFF0000u);
    }
    #pragma unroll
    for (int j = 0; j < 4; ++j) {
        unsigned int pk;
        asm("v_cvt_pk_bf16_f32 %0, %1, %2"
            : "=v"(pk) : "v"(lf[2 * j]), "v"(lf[2 * j + 1]));
        lp[j] = pk;
    }
    hi = __builtin_bit_cast(short8, hp);
    lo = __builtin_bit_cast(short8, lp);
}

__global__ __launch_bounds__(256, 4)
void fused_mention_kernel(const float* __restrict__ E,
                          const float* __restrict__ T,
                          const void*  __restrict__ maskp,
                          const float* __restrict__ B1,
                          const float* __restrict__ B2,
                          float* __restrict__ out)
{
    const int n     = blockIdx.x;
    const int tid   = threadIdx.x;
    const int wv    = tid >> 6;
    const int lane  = tid & 63;
    const int arow  = lane & 31;          // candidate row (A) / token col (B)
    const int khalf = (lane >> 5) * 8;

    __shared__ __align__(16) short Ah[NC * AST];   // 18.7 KB bf16-hi of E*B2
    __shared__ __align__(16) short Al[NC * AST];   // 18.7 KB bf16-lo
    __shared__ __align__(16) float fcsL[D];        // fallback path only
    __shared__ float ts[WIN];
    __shared__ float bscore[TOPK];
    __shared__ int   bidx[TOPK];
    __shared__ float bprob[TOPK];
    __shared__ float vredS[4][32];

    if (tid < WIN) ts[tid] = NEGV;        // covered by the stage barrier below

    // ---- mask dtype detect, per-wave (no barrier): int32 has zero bytes %4!=0 ----
    int found;
    {
        const uint4v* m4 = (const uint4v*)maskp;
        uint4v w = m4[wv * 64 + lane];    // wave w scans bytes [1024w, 1024w+1024)
        found = (((w.x | w.y | w.z | w.w) & 0xFFFFFF00u) != 0u) ? 1 : 0;
    }
    const bool bytemask = (__ballot(found) != 0ULL);

    // ---- valid-prefix length L, per-wave (redundant, L1-hot, no LDS) ----
    int v0m = 0, v1m = 0;
    if (bytemask) {
        const unsigned char* mb = (const unsigned char*)maskp + (size_t)n * WIN;
        v0m = mb[lane] != 0;
        if (lane + 64 < WIN) v1m = mb[lane + 64] != 0;
    } else {
        const int* mi = (const int*)maskp + (size_t)n * WIN;
        v0m = mi[lane] != 0;
        if (lane + 64 < WIN) v1m = mi[lane + 64] != 0;
    }
    const int L  = __popcll(__ballot(v0m)) + __popcll(__ballot(v1m));
    const int Lc = (L > 0) ? L : 1;

    // ---- B1 == B2 check (enables vals-from-scores identity) ----
    int neq = 0;
    #pragma unroll
    for (int k = 0; k < 5; ++k) {
        const int d = lane + 64 * k;
        if (d < D) neq |= (B1[d] != B2[d]) ? 1 : 0;
    }
    const bool beq = (__ballot(neq) == 0ULL);   // block-uniform (global data)

    // ---- stage A = E * B_diag2 into LDS as bf16 hi/lo ----
    {
        const int srow = tid & 31;        // rows 30,31 idle (16 threads)
        const int scol = tid >> 5;        // 0..7
        if (srow < NC) {
            #pragma unroll
            for (int k = 0; k < 5; ++k) {
                const int c8 = scol + 8 * k;          // 0..39
                if (c8 < 38) {
                    const int col = c8 * 8;
                    const float* src = E + ((size_t)n * NC + srow) * D + col;
                    float v[8];
                    float4 q0 = *reinterpret_cast<const float4*>(src);
                    float4 b0 = *reinterpret_cast<const float4*>(B2 + col);
                    v[0] = q0.x * b0.x; v[1] = q0.y * b0.y;
                    v[2] = q0.z * b0.z; v[3] = q0.w * b0.w;
                    if (c8 < 37) {
                        float4 q1 = *reinterpret_cast<const float4*>(src + 4);
                        float4 b1 = *reinterpret_cast<const float4*>(B2 + col + 4);
                        v[4] = q1.x * b1.x; v[5] = q1.y * b1.y;
                        v[6] = q1.z * b1.z; v[7] = q1.w * b1.w;
                    } else {
                        v[4] = v[5] = v[6] = v[7] = 0.f;   // cols 300..303 zero
                    }
                    short8 hi, lo;
                    split8(v, hi, lo);
                    *reinterpret_cast<short8*>(Ah + srow * AST + col) = hi;
                    *reinterpret_cast<short8*>(Al + srow * AST + col) = lo;
                }
            }
        }
    }

    const int ntiles = (L + 31) >> 5;
    const int t0 = wv * 32;
    const float* Tn = T + (size_t)n * WIN * D;
    const float* bp = Tn + (size_t)min(t0 + arow, Lc - 1) * D;

    // ---- preload GEMM ring steps 0..7 BEFORE the barrier (covers HBM latency) ----
    float4 q0r[8], q1r[8];
    if (wv < ntiles) {
        #pragma unroll
        for (int s = 0; s < 8; ++s) {             // kb max 112+8=120, kb+8 <= 300 safe
            const int kb = 16 * s + khalf;
            q0r[s] = *reinterpret_cast<const float4*>(bp + kb);
            q1r[s] = *reinterpret_cast<const float4*>(bp + kb + 4);
        }
    }
    __syncthreads();                                  // A staged, ts init'd

    // ---- score GEMM: wave wv owns tile wv; 8-step prefetch ring ----
    f32x16 c;
    #pragma unroll
    for (int r = 0; r < 16; ++r) c[r] = 0.f;
    if (wv < ntiles) {
        const int aoff = min(arow, NC - 1) * AST + khalf;   // rows 30,31 clamp (masked)
        #pragma unroll
        for (int s = 0; s < NKS; ++s) {
            const int slot = s & 7;                   // static after unroll
            float4 q0 = q0r[slot], q1 = q1r[slot];
            if (s + 8 < NKS) {                        // prefetch step s+8
                const int kb2 = 16 * (s + 8) + khalf;
                q0r[slot] = *reinterpret_cast<const float4*>(bp + kb2);
                q1r[slot] = (kb2 + 8 <= D)
                          ? *reinterpret_cast<const float4*>(bp + kb2 + 4)
                          : make_float4(0.f, 0.f, 0.f, 0.f);
            }
            short8 ah = *reinterpret_cast<const short8*>(Ah + aoff + 16 * s);
            short8 al = *reinterpret_cast<const short8*>(Al + aoff + 16 * s);
            float v[8] = {q0.x, q0.y, q0.z, q0.w, q1.x, q1.y, q1.z, q1.w};
            short8 bh, bl;
            split8(v, bh, bl);
            c = __builtin_amdgcn_mfma_f32_32x32x16_bf16(ah, bh, c, 0, 0, 0);
            c = __builtin_amdgcn_mfma_f32_32x32x16_bf16(al, bh, c, 0, 0, 0);
            c = __builtin_amdgcn_mfma_f32_32x32x16_bf16(ah, bl, c, 0, 0, 0);
        }
        // pad candidate rows 30,31 (regs 14,15 on lanes >= 32) -> -inf
        if (lane >= 32) { c[14] = -__builtin_inff(); c[15] = -__builtin_inff(); }
        float m = c[0];
        #pragma unroll
        for (int r = 1; r < 16; ++r) m = fmaxf(m, c[r]);
        m = fmaxf(m, __shfl_xor(m, 32));
        if (lane < 32 && t0 + arow < L) ts[t0 + arow] = m;
    }
    __syncthreads();                                  // ts complete

    // ---- top-25 (wave 0, lower-index tie-break) + double-normalized softmax ----
    if (tid < 64) {
        float va = ts[tid];
        float vb = (tid + 64 < WIN) ? ts[tid + 64] : -__builtin_inff();
        float mx = 0.f;
        for (int t = 0; t < TOPK; ++t) {
            float v0; int i0;
            if (vb > va) { v0 = vb; i0 = tid + 64; } else { v0 = va; i0 = tid; }
            #pragma unroll
            for (int s = 32; s >= 1; s >>= 1) {
                float ov = __shfl_xor(v0, s);
                int   oi = __shfl_xor(i0, s);
                if (ov > v0 || (ov == v0 && oi < i0)) { v0 = ov; i0 = oi; }
            }
            if (t == 0) mx = v0;
            if (tid == 0) { bscore[t] = v0; bidx[t] = i0; }
            if (i0 == tid) va = -__builtin_inff();
            else if (i0 == tid + 64) vb = -__builtin_inff();
        }
        float sc = (tid < TOPK) ? bscore[tid] : 0.f;
        float p  = (tid < TOPK) ? expf(sc - mx) : 0.f;
        float s1 = p;
        #pragma unroll
        for (int s = 32; s >= 1; s >>= 1) s1 += __shfl_xor(s1, s);
        p = p / s1;
        float s2 = p;   // reference renormalizes a second time
        #pragma unroll
        for (int s = 32; s >= 1; s >>= 1) s2 += __shfl_xor(s2, s);
        p = p / s2;
        if (tid < TOPK) bprob[tid] = p;
    }
    __syncthreads();                                  // bprob/bidx visible

    if (beq) {
        // ---- vals[c] = sum_t p_t * S[c, idx_t] straight from the accumulators ----
        float vacc[16];
        #pragma unroll
        for (int r = 0; r < 16; ++r) vacc[r] = 0.f;
        if (wv < ntiles) {
            for (int t = 0; t < TOPK; ++t) {
                const int ix = bidx[t];
                if ((ix >> 5) == wv) {                // wave-uniform branch
                    const float p = bprob[t];
                    if ((lane & 31) == (ix & 31)) {   // owning lanes (2 of 64)
                        #pragma unroll
                        for (int r = 0; r < 16; ++r) vacc[r] += p * c[r];
                    }
                }
            }
        }
        // butterfly-sum within each 32-lane half (rows differ per half)
        #pragma unroll
        for (int r = 0; r < 16; ++r) {
            float s = vacc[r];
            s += __shfl_xor(s, 1);  s += __shfl_xor(s, 2);
            s += __shfl_xor(s, 4);  s += __shfl_xor(s, 8);
            s += __shfl_xor(s, 16);
            vacc[r] = s;
        }
        if ((lane & 31) == 0) {                       // lanes 0 and 32
            #pragma unroll
            for (int r = 0; r < 16; ++r) {
                const int row = (r & 3) + 8 * (r >> 2) + 4 * (lane >> 5);
                vredS[wv][row] = vacc[r];
            }
        }
        __syncthreads();
        if (tid < NC) {
            out[(size_t)n * NC + tid] = vredS[0][tid] + vredS[1][tid]
                                      + vredS[2][tid] + vredS[3][tid];
        }
    } else {
        // ---- fallback (B1 != B2): fcs gather + vals with E re-read ----
        for (int d = tid; d < D; d += 256) {
            float acc = 0.f;
            #pragma unroll 5
            for (int t = 0; t < TOPK; ++t)
                acc += bprob[t] * Tn[(size_t)bidx[t] * D + d];
            fcsL[d] = acc;
        }
        __syncthreads();
        {
            const int dg = tid >> 5;
            const int d0 = dg * 40;
            const bool full = (dg < 7);
            const int cg = arow;
            const bool cok = (cg < NC);
            float acc2 = 0.f;
            const float* Erow = E + ((size_t)n * NC + (cok ? cg : 0)) * D + d0;
            #pragma unroll
            for (int j = 0; j < 5; ++j) {
                float4 ev = *reinterpret_cast<const float4*>(Erow + 4 * j);
                float4 bv = *reinterpret_cast<const float4*>(B1 + d0 + 4 * j);
                float4 fv = *reinterpret_cast<const float4*>(fcsL + d0 + 4 * j);
                acc2 += ev.x * bv.x * fv.x + ev.y * bv.y * fv.y
                      + ev.z * bv.z * fv.z + ev.w * bv.w * fv.w;
            }
            if (full) {
                #pragma unroll
                for (int j = 5; j < 10; ++j) {
                    float4 ev = *reinterpret_cast<const float4*>(Erow + 4 * j);
                    float4 bv = *reinterpret_cast<const float4*>(B1 + d0 + 4 * j);
                    float4 fv = *reinterpret_cast<const float4*>(fcsL + d0 + 4 * j);
                    acc2 += ev.x * bv.x * fv.x + ev.y * bv.y * fv.y
                          + ev.z * bv.z * fv.z + ev.w * bv.w * fv.w;
                }
            }
            if (!cok) acc2 = 0.f;
            acc2 += __shfl_xor(acc2, 32);
            if (lane < 32) vredS[wv][cg] = acc2;
        }
        __syncthreads();
        if (tid < NC) {
            out[(size_t)n * NC + tid] = vredS[0][tid] + vredS[1][tid]
                                      + vredS[2][tid] + vredS[3][tid];
        }
    }
}

extern "C" void kernel_launch(void* const* d_in, const int* in_sizes, int n_in,
                              void* d_out, int out_size, void* d_ws, size_t ws_size,
                              hipStream_t stream)
{
    const float* E  = (const float*)d_in[0];
    const float* T  = (const float*)d_in[1];
    const void*  M  = d_in[2];
    const float* B1 = (const float*)d_in[3];
    const float* B2 = (const float*)d_in[4];
    float* out = (float*)d_out;
    const int n = in_sizes[0] / (NC * D);   // number of mentions
    fused_mention_kernel<<<n, 256, 0, stream>>>(E, T, M, B1, B2, out);
}